// Round 1
// baseline (382.086 us; speedup 1.0000x reference)
//
#include <hip/hip_runtime.h>
#include <hip/hip_bf16.h>
#include <cstdint>
#include <cstddef>

#define NV 4096
#define DE 256
#define MAXNNZ 512

// ---------------- CSR build: one wave per row, ballot-compact ----------------
__global__ __launch_bounds__(256) void build_csr(const float* __restrict__ adj,
                                                 int* __restrict__ cols,
                                                 int* __restrict__ nnz)
{
    int wave = threadIdx.x >> 6;
    int lane = threadIdx.x & 63;
    int row  = blockIdx.x * 4 + wave;
    const float* arow = adj + (size_t)row * NV;
    int* crow = cols + (size_t)row * MAXNNZ;
    int base = 0;
    for (int c0 = 0; c0 < NV; c0 += 64) {
        float v = arow[c0 + lane];
        bool pred = v > 0.0f;
        unsigned long long m = __ballot(pred);
        int idx = base + __popcll(m & ((1ull << lane) - 1ull));
        if (pred && idx < MAXNNZ) crow[idx] = c0 + lane;
        base += __popcll(m);
    }
    if (lane == 0) nnz[row] = base < MAXNNZ ? base : MAXNNZ;
}

// ---------------- f32 tiled GEMM: C[M,N] = A[M,K] @ B[K,N] ----------------
#define BM 64
#define BN 64
#define BK 16

__global__ __launch_bounds__(256) void sgemm(const float* __restrict__ A,
                                             const float* __restrict__ B,
                                             float* __restrict__ C,
                                             int M, int Nn, int K)
{
    __shared__ float As[BK][BM];   // A tile, transposed (k-major)
    __shared__ float Bs[BK][BN];

    const int bm  = blockIdx.y * BM;
    const int bn  = blockIdx.x * BN;
    const int tid = threadIdx.x;

    // A tile load mapping: 64 rows x 16 k, float4 along k
    const int a_m = tid >> 2;          // 0..63
    const int a_k = (tid & 3) << 2;    // 0,4,8,12
    // B tile load mapping: 16 k x 64 n, float4 along n
    const int b_k = tid >> 4;          // 0..15
    const int b_n = (tid & 15) << 2;   // 0..60

    const int ty = tid >> 4;           // 0..15 -> row group
    const int tx = tid & 15;           // 0..15 -> col group

    float acc[4][4] = {};

    for (int k0 = 0; k0 < K; k0 += BK) {
        float4 av = *reinterpret_cast<const float4*>(&A[(size_t)(bm + a_m) * K + k0 + a_k]);
        float4 bv = *reinterpret_cast<const float4*>(&B[(size_t)(k0 + b_k) * Nn + bn + b_n]);
        As[a_k + 0][a_m] = av.x;
        As[a_k + 1][a_m] = av.y;
        As[a_k + 2][a_m] = av.z;
        As[a_k + 3][a_m] = av.w;
        *reinterpret_cast<float4*>(&Bs[b_k][b_n]) = bv;
        __syncthreads();

#pragma unroll
        for (int k = 0; k < BK; ++k) {
            float4 a4 = *reinterpret_cast<const float4*>(&As[k][ty * 4]);
            float4 b4 = *reinterpret_cast<const float4*>(&Bs[k][tx * 4]);
            float am[4] = {a4.x, a4.y, a4.z, a4.w};
            float bb[4] = {b4.x, b4.y, b4.z, b4.w};
#pragma unroll
            for (int i = 0; i < 4; ++i)
#pragma unroll
                for (int j = 0; j < 4; ++j)
                    acc[i][j] = fmaf(am[i], bb[j], acc[i][j]);
        }
        __syncthreads();
    }

#pragma unroll
    for (int i = 0; i < 4; ++i) {
        float4 o = make_float4(acc[i][0], acc[i][1], acc[i][2], acc[i][3]);
        *reinterpret_cast<float4*>(&C[(size_t)(bm + ty * 4 + i) * Nn + bn + tx * 4]) = o;
    }
}

// ---------------- f_src / f_dst: one wave per row ----------------
__global__ __launch_bounds__(256) void fsd_kernel(const float* __restrict__ Wh,
                                                  const float* __restrict__ a,
                                                  float* __restrict__ fs,
                                                  float* __restrict__ fd)
{
    int wave = threadIdx.x >> 6;
    int lane = threadIdx.x & 63;
    int row  = blockIdx.x * 4 + wave;
    float4 w  = *reinterpret_cast<const float4*>(&Wh[(size_t)row * DE + lane * 4]);
    float4 at = *reinterpret_cast<const float4*>(&a[lane * 4]);
    float4 ab = *reinterpret_cast<const float4*>(&a[DE + lane * 4]);
    float s = w.x * at.x + w.y * at.y + w.z * at.z + w.w * at.w;
    float d = w.x * ab.x + w.y * ab.y + w.z * ab.z + w.w * ab.w;
#pragma unroll
    for (int off = 32; off; off >>= 1) {
        s += __shfl_down(s, off);
        d += __shfl_down(d, off);
    }
    if (lane == 0) { fs[row] = s; fd[row] = d; }
}

// ---------------- fused masked-softmax + SpMM + activation ----------------
// ACT: 0 = ELU, 1 = ReLU (== relu(elu(z)))
template <int ACT>
__global__ __launch_bounds__(256) void attn_spmm(const float* __restrict__ Wh,
                                                 const float* __restrict__ fs,
                                                 const float* __restrict__ fd,
                                                 const int* __restrict__ cols,
                                                 const int* __restrict__ nnzArr,
                                                 float* __restrict__ out)
{
    __shared__ float p[MAXNNZ];
    __shared__ int   ci[MAXNNZ];
    __shared__ float red[4];

    const int row = blockIdx.x;
    const int t   = threadIdx.x;
    const int lane = t & 63;
    const int wv   = t >> 6;
    const int n   = nnzArr[row];
    const int* rc = cols + (size_t)row * MAXNNZ;
    const float fsi = fs[row];

    // phase 1: e = leakyrelu(fs_i + fd_j), row max
    float lm = -1e30f;
    for (int j = t; j < n; j += 256) {
        int c = rc[j];
        ci[j] = c;
        float e = fsi + fd[c];
        e = (e >= 0.0f) ? e : 0.2f * e;
        p[j] = e;
        lm = fmaxf(lm, e);
    }
#pragma unroll
    for (int off = 32; off; off >>= 1) lm = fmaxf(lm, __shfl_down(lm, off));
    if (lane == 0) red[wv] = lm;
    __syncthreads();
    const float m = fmaxf(fmaxf(red[0], red[1]), fmaxf(red[2], red[3]));
    __syncthreads();

    // phase 2: exp + sum
    float ls = 0.0f;
    for (int j = t; j < n; j += 256) {
        float pe = expf(p[j] - m);
        p[j] = pe;
        ls += pe;
    }
#pragma unroll
    for (int off = 32; off; off >>= 1) ls += __shfl_down(ls, off);
    if (lane == 0) red[wv] = ls;
    __syncthreads();
    const float invZ = 1.0f / (red[0] + red[1] + red[2] + red[3]);

    // phase 3: out_row[d] = (1/Z) * sum_j p_j * Wh[col_j, d]
    const int d = t;
    float acc = 0.0f;
    int j = 0;
    for (; j + 4 <= n; j += 4) {
        float p0 = p[j], p1 = p[j + 1], p2 = p[j + 2], p3 = p[j + 3];
        int   c0 = ci[j], c1 = ci[j + 1], c2 = ci[j + 2], c3 = ci[j + 3];
        float w0 = Wh[(size_t)c0 * DE + d];
        float w1 = Wh[(size_t)c1 * DE + d];
        float w2 = Wh[(size_t)c2 * DE + d];
        float w3 = Wh[(size_t)c3 * DE + d];
        acc = fmaf(p0, w0, acc);
        acc = fmaf(p1, w1, acc);
        acc = fmaf(p2, w2, acc);
        acc = fmaf(p3, w3, acc);
    }
    for (; j < n; ++j) acc = fmaf(p[j], Wh[(size_t)ci[j] * DE + d], acc);
    acc *= invZ;

    float r;
    if (ACT == 0) r = (acc > 0.0f) ? acc : expm1f(acc);
    else          r = (acc > 0.0f) ? acc : 0.0f;
    out[(size_t)row * DE + d] = r;
}

// ---------------- launch ----------------
extern "C" void kernel_launch(void* const* d_in, const int* in_sizes, int n_in,
                              void* d_out, int out_size, void* d_ws, size_t ws_size,
                              hipStream_t stream)
{
    const float* x   = (const float*)d_in[0];
    const float* adj = (const float*)d_in[1];
    const float* W11 = (const float*)d_in[2];
    const float* a11 = (const float*)d_in[3];
    const float* W12 = (const float*)d_in[4];
    const float* a12 = (const float*)d_in[5];
    const float* W21 = (const float*)d_in[6];
    const float* a21 = (const float*)d_in[7];
    const float* W22 = (const float*)d_in[8];
    const float* a22 = (const float*)d_in[9];
    float* out = (float*)d_out;

    char* ws = (char*)d_ws;
    int*   cols = (int*)ws;                                        // 4096*512*4 = 8 MB
    int*   nnz  = (int*)(ws + (size_t)NV * MAXNNZ * 4);            // 16 KB
    float* fs   = (float*)(ws + (size_t)NV * MAXNNZ * 4 + 64 * 1024);
    float* fd   = fs + NV;
    float* Wh   = (float*)(ws + (size_t)NV * MAXNNZ * 4 + 128 * 1024);  // 4 MB
    float* hA   = Wh + (size_t)NV * DE;                            // 4 MB
    float* hB   = hA + (size_t)NV * DE;                            // 4 MB

    dim3 gemmGrid(DE / BN, NV / BM);

    build_csr<<<NV / 4, 256, 0, stream>>>(adj, cols, nnz);

    // GAT 1, layer 1 (K = 4096)
    sgemm<<<gemmGrid, 256, 0, stream>>>(x, W11, Wh, NV, DE, NV);
    fsd_kernel<<<NV / 4, 256, 0, stream>>>(Wh, a11, fs, fd);
    attn_spmm<0><<<NV, 256, 0, stream>>>(Wh, fs, fd, cols, nnz, hA);

    // GAT 1, layer 2 + fused ReLU (relu(elu(z)) == relu(z))
    sgemm<<<gemmGrid, 256, 0, stream>>>(hA, W12, Wh, NV, DE, DE);
    fsd_kernel<<<NV / 4, 256, 0, stream>>>(Wh, a12, fs, fd);
    attn_spmm<1><<<NV, 256, 0, stream>>>(Wh, fs, fd, cols, nnz, hB);

    // GAT 2, layer 1
    sgemm<<<gemmGrid, 256, 0, stream>>>(hB, W21, Wh, NV, DE, DE);
    fsd_kernel<<<NV / 4, 256, 0, stream>>>(Wh, a21, fs, fd);
    attn_spmm<0><<<NV, 256, 0, stream>>>(Wh, fs, fd, cols, nnz, hA);

    // GAT 2, layer 2 -> output
    sgemm<<<gemmGrid, 256, 0, stream>>>(hA, W22, Wh, NV, DE, DE);
    fsd_kernel<<<NV / 4, 256, 0, stream>>>(Wh, a22, fs, fd);
    attn_spmm<0><<<NV, 256, 0, stream>>>(Wh, fs, fd, cols, nnz, out);
}

// Round 2
// 228.282 us; speedup vs baseline: 1.6737x; 1.6737x over previous
//
#include <hip/hip_runtime.h>
#include <hip/hip_bf16.h>
#include <cstdint>
#include <cstddef>

#define NV 4096
#define DE 256
#define MAXNNZ 192

typedef __attribute__((ext_vector_type(8))) short bf16x8;
typedef __attribute__((ext_vector_type(4))) float f32x4;

__device__ __forceinline__ unsigned short f2bf(float f) {
    unsigned int u = __float_as_uint(f);
    u += 0x7fff + ((u >> 16) & 1);           // round-to-nearest-even
    return (unsigned short)(u >> 16);
}
__device__ __forceinline__ float bf2f(unsigned short h) {
    return __uint_as_float(((unsigned int)h) << 16);
}

// ---------------- CSR build: one wave per row, ballot-compact ----------------
__global__ __launch_bounds__(256) void build_csr(const float* __restrict__ adj,
                                                 int* __restrict__ cols,
                                                 int* __restrict__ nnz)
{
    int wave = threadIdx.x >> 6;
    int lane = threadIdx.x & 63;
    int row  = blockIdx.x * 4 + wave;
    const float* arow = adj + (size_t)row * NV;
    int* crow = cols + (size_t)row * MAXNNZ;
    int base = 0;
    for (int c0 = 0; c0 < NV; c0 += 64) {
        float v = arow[c0 + lane];
        bool pred = v > 0.0f;
        unsigned long long m = __ballot(pred);
        int idx = base + __popcll(m & ((1ull << lane) - 1ull));
        if (pred && idx < MAXNNZ) crow[idx] = c0 + lane;
        base += __popcll(m);
    }
    if (lane == 0) nnz[row] = base < MAXNNZ ? base : MAXNNZ;
}

// ------------- W transpose + bf16 hi/lo split: [K][256] f32 -> [256][K] -------------
__global__ __launch_bounds__(256) void transp_split(const float* __restrict__ W,
                                                    unsigned short* __restrict__ bh,
                                                    unsigned short* __restrict__ bl,
                                                    int K)
{
    __shared__ float tile[32][33];
    const int k0 = blockIdx.x * 32, n0 = blockIdx.y * 32;
    const int t = threadIdx.x;
    {
        int r = t >> 3, cq = t & 7;
        float4 v = *(const float4*)&W[(size_t)(k0 + r) * DE + n0 + cq * 4];
        tile[r][cq * 4 + 0] = v.x;
        tile[r][cq * 4 + 1] = v.y;
        tile[r][cq * 4 + 2] = v.z;
        tile[r][cq * 4 + 3] = v.w;
    }
    __syncthreads();
    {
        int nl = t >> 3, kq = t & 7;
        ushort4 hv, lv;
        float x0 = tile[kq * 4 + 0][nl];
        float x1 = tile[kq * 4 + 1][nl];
        float x2 = tile[kq * 4 + 2][nl];
        float x3 = tile[kq * 4 + 3][nl];
        hv.x = f2bf(x0); lv.x = f2bf(x0 - bf2f(hv.x));
        hv.y = f2bf(x1); lv.y = f2bf(x1 - bf2f(hv.y));
        hv.z = f2bf(x2); lv.z = f2bf(x2 - bf2f(hv.z));
        hv.w = f2bf(x3); lv.w = f2bf(x3 - bf2f(hv.w));
        size_t o = (size_t)(n0 + nl) * K + k0 + kq * 4;
        *(ushort4*)&bh[o] = hv;
        *(ushort4*)&bl[o] = lv;
    }
}

// ---------------- split-bf16 MFMA GEMM ----------------
// C[M=4096][256] (+= over split-K partials) = A[4096][K] f32  x  B (given as
// Bt hi/lo [256][K] bf16, k-major).  Block tile 64x128, BK=32, 4 waves of 32x64.
// LDS: [row][64] u16 per matrix; cols 0..31 = hi (subs 0..3), 32..63 = lo (subs 4..7),
// 16B-chunk index XOR-swizzled with (row&7).
#define BM 64
#define BN 128
#define BK 32

__global__ __launch_bounds__(256) void gemm_split(const float* __restrict__ A,
                                                  const unsigned short* __restrict__ Bh,
                                                  const unsigned short* __restrict__ Bl,
                                                  float* __restrict__ C,
                                                  int K, int Kchunk)
{
    __shared__ __align__(16) unsigned short sA[64 * 64];
    __shared__ __align__(16) unsigned short sB[128 * 64];

    const int t    = threadIdx.x;
    const int lane = t & 63;
    const int wid  = t >> 6;
    const int wr   = wid >> 1;      // 0..1
    const int wc   = wid & 1;       // 0..1
    const int bn   = blockIdx.x * BN;
    const int bm   = blockIdx.y * BM;
    const int kz   = blockIdx.z;
    const int kbeg = kz * Kchunk;
    const int nsteps = Kchunk / BK;

    // staging maps
    const int ar = t >> 2;               // 0..63  (A tile row)
    const int as = t & 3;                // A k-chunk (8 f32)
    const int br = t >> 1;               // 0..127 (B tile row = output col)
    const int bhf = t & 1;               // B half (16 bf16)

    const float*          Ap  = A  + (size_t)(bm + ar) * K + kbeg + as * 8;
    const unsigned short* Bhp = Bh + (size_t)(bn + br) * K + kbeg + bhf * 16;
    const unsigned short* Blp = Bl + (size_t)(bn + br) * K + kbeg + bhf * 16;

    // LDS write offsets (u16 units)
    const int aw_h = ar * 64 + (((as)     ^ (ar & 7)) << 3);
    const int aw_l = ar * 64 + (((as | 4) ^ (ar & 7)) << 3);
    const int bs0  = bhf * 2;
    const int bw_h0 = br * 64 + (((bs0)         ^ (br & 7)) << 3);
    const int bw_h1 = br * 64 + (((bs0 + 1)     ^ (br & 7)) << 3);
    const int bw_l0 = br * 64 + ((((bs0) | 4)   ^ (br & 7)) << 3);
    const int bw_l1 = br * 64 + ((((bs0 + 1) | 4) ^ (br & 7)) << 3);

    // frag read offsets
    const int fr = lane & 15, fsub = lane >> 4;
    const int arow0 = wr * 32 + fr;
    const int arow1 = arow0 + 16;
    const int ard0h = arow0 * 64 + (((fsub)     ^ (arow0 & 7)) << 3);
    const int ard0l = arow0 * 64 + (((fsub | 4) ^ (arow0 & 7)) << 3);
    const int ard1h = arow1 * 64 + (((fsub)     ^ (arow1 & 7)) << 3);
    const int ard1l = arow1 * 64 + (((fsub | 4) ^ (arow1 & 7)) << 3);

    // prologue loads
    float4 a0 = *(const float4*)(Ap);
    float4 a1 = *(const float4*)(Ap + 4);
    bf16x8 g_bh0 = *(const bf16x8*)(Bhp);
    bf16x8 g_bh1 = *(const bf16x8*)(Bhp + 8);
    bf16x8 g_bl0 = *(const bf16x8*)(Blp);
    bf16x8 g_bl1 = *(const bf16x8*)(Blp + 8);

    f32x4 acc[2][4];
#pragma unroll
    for (int i = 0; i < 2; ++i)
#pragma unroll
        for (int j = 0; j < 4; ++j) acc[i][j] = (f32x4){0.f, 0.f, 0.f, 0.f};

    for (int s = 0; s < nsteps; ++s) {
        __syncthreads();   // previous step's LDS readers done
        {   // convert + store A
            float xs0 = a0.x, xs1 = a0.y, xs2 = a0.z, xs3 = a0.w;
            float xs4 = a1.x, xs5 = a1.y, xs6 = a1.z, xs7 = a1.w;
            bf16x8 hv, lv;
            unsigned short h;
            h = f2bf(xs0); hv[0] = (short)h; lv[0] = (short)f2bf(xs0 - bf2f(h));
            h = f2bf(xs1); hv[1] = (short)h; lv[1] = (short)f2bf(xs1 - bf2f(h));
            h = f2bf(xs2); hv[2] = (short)h; lv[2] = (short)f2bf(xs2 - bf2f(h));
            h = f2bf(xs3); hv[3] = (short)h; lv[3] = (short)f2bf(xs3 - bf2f(h));
            h = f2bf(xs4); hv[4] = (short)h; lv[4] = (short)f2bf(xs4 - bf2f(h));
            h = f2bf(xs5); hv[5] = (short)h; lv[5] = (short)f2bf(xs5 - bf2f(h));
            h = f2bf(xs6); hv[6] = (short)h; lv[6] = (short)f2bf(xs6 - bf2f(h));
            h = f2bf(xs7); hv[7] = (short)h; lv[7] = (short)f2bf(xs7 - bf2f(h));
            *(bf16x8*)&sA[aw_h] = hv;
            *(bf16x8*)&sA[aw_l] = lv;
        }
        *(bf16x8*)&sB[bw_h0] = g_bh0;
        *(bf16x8*)&sB[bw_h1] = g_bh1;
        *(bf16x8*)&sB[bw_l0] = g_bl0;
        *(bf16x8*)&sB[bw_l1] = g_bl1;
        __syncthreads();

        if (s + 1 < nsteps) {   // prefetch next tile (hidden under MFMA)
            Ap += BK; Bhp += BK; Blp += BK;
            a0 = *(const float4*)(Ap);
            a1 = *(const float4*)(Ap + 4);
            g_bh0 = *(const bf16x8*)(Bhp);
            g_bh1 = *(const bf16x8*)(Bhp + 8);
            g_bl0 = *(const bf16x8*)(Blp);
            g_bl1 = *(const bf16x8*)(Blp + 8);
        }

        bf16x8 ah0 = *(const bf16x8*)&sA[ard0h];
        bf16x8 al0 = *(const bf16x8*)&sA[ard0l];
        bf16x8 ah1 = *(const bf16x8*)&sA[ard1h];
        bf16x8 al1 = *(const bf16x8*)&sA[ard1l];
        bf16x8 bhv[4], blv[4];
#pragma unroll
        for (int ni = 0; ni < 4; ++ni) {
            int n = wc * 64 + ni * 16 + fr;
            bhv[ni] = *(const bf16x8*)&sB[n * 64 + (((fsub)     ^ (n & 7)) << 3)];
            blv[ni] = *(const bf16x8*)&sB[n * 64 + (((fsub | 4) ^ (n & 7)) << 3)];
        }
#pragma unroll
        for (int ni = 0; ni < 4; ++ni) {
            acc[0][ni] = __builtin_amdgcn_mfma_f32_16x16x32_bf16(ah0, bhv[ni], acc[0][ni], 0, 0, 0);
            acc[0][ni] = __builtin_amdgcn_mfma_f32_16x16x32_bf16(ah0, blv[ni], acc[0][ni], 0, 0, 0);
            acc[0][ni] = __builtin_amdgcn_mfma_f32_16x16x32_bf16(al0, bhv[ni], acc[0][ni], 0, 0, 0);
            acc[1][ni] = __builtin_amdgcn_mfma_f32_16x16x32_bf16(ah1, bhv[ni], acc[1][ni], 0, 0, 0);
            acc[1][ni] = __builtin_amdgcn_mfma_f32_16x16x32_bf16(ah1, blv[ni], acc[1][ni], 0, 0, 0);
            acc[1][ni] = __builtin_amdgcn_mfma_f32_16x16x32_bf16(al1, bhv[ni], acc[1][ni], 0, 0, 0);
        }
    }

    // epilogue: C/D layout (verified): col = lane&15, row = (lane>>4)*4 + reg
    float* Cb = C + (size_t)kz * NV * DE;
#pragma unroll
    for (int mi = 0; mi < 2; ++mi) {
#pragma unroll
        for (int ni = 0; ni < 4; ++ni) {
            int row = bm + wr * 32 + mi * 16 + (fsub << 2);
            int col = bn + wc * 64 + ni * 16 + fr;
#pragma unroll
            for (int i = 0; i < 4; ++i)
                Cb[(size_t)(row + i) * DE + col] = acc[mi][ni][i];
        }
    }
}

// ---------------- split-K reduce (S=2) fused with f_src/f_dst ----------------
__global__ __launch_bounds__(256) void reduce_fsd(const float* __restrict__ Cp,
                                                  const float* __restrict__ a,
                                                  float* __restrict__ Wh,
                                                  float* __restrict__ fs,
                                                  float* __restrict__ fd)
{
    int wid = threadIdx.x >> 6, lane = threadIdx.x & 63;
    int row = blockIdx.x * 4 + wid;
    size_t idx = (size_t)row * DE + lane * 4;
    float4 p0 = *(const float4*)&Cp[idx];
    float4 p1 = *(const float4*)&Cp[(size_t)NV * DE + idx];
    float4 w;
    w.x = p0.x + p1.x; w.y = p0.y + p1.y; w.z = p0.z + p1.z; w.w = p0.w + p1.w;
    *(float4*)&Wh[idx] = w;
    float4 at = *(const float4*)&a[lane * 4];
    float4 ab = *(const float4*)&a[DE + lane * 4];
    float s = w.x * at.x + w.y * at.y + w.z * at.z + w.w * at.w;
    float d = w.x * ab.x + w.y * ab.y + w.z * ab.z + w.w * ab.w;
#pragma unroll
    for (int off = 32; off; off >>= 1) {
        s += __shfl_down(s, off);
        d += __shfl_down(d, off);
    }
    if (lane == 0) { fs[row] = s; fd[row] = d; }
}

// ---------------- f_src / f_dst only ----------------
__global__ __launch_bounds__(256) void fsd_kernel(const float* __restrict__ Wh,
                                                  const float* __restrict__ a,
                                                  float* __restrict__ fs,
                                                  float* __restrict__ fd)
{
    int wave = threadIdx.x >> 6;
    int lane = threadIdx.x & 63;
    int row  = blockIdx.x * 4 + wave;
    float4 w  = *(const float4*)&Wh[(size_t)row * DE + lane * 4];
    float4 at = *(const float4*)&a[lane * 4];
    float4 ab = *(const float4*)&a[DE + lane * 4];
    float s = w.x * at.x + w.y * at.y + w.z * at.z + w.w * at.w;
    float d = w.x * ab.x + w.y * ab.y + w.z * ab.z + w.w * ab.w;
#pragma unroll
    for (int off = 32; off; off >>= 1) {
        s += __shfl_down(s, off);
        d += __shfl_down(d, off);
    }
    if (lane == 0) { fs[row] = s; fd[row] = d; }
}

// ---------------- fused masked-softmax + SpMM + activation ----------------
template <int ACT>   // 0 = ELU, 1 = ReLU
__global__ __launch_bounds__(256) void attn_spmm(const float* __restrict__ Wh,
                                                 const float* __restrict__ fs,
                                                 const float* __restrict__ fd,
                                                 const int* __restrict__ cols,
                                                 const int* __restrict__ nnzArr,
                                                 float* __restrict__ out)
{
    __shared__ float p[MAXNNZ];
    __shared__ int   ci[MAXNNZ];
    __shared__ float red[4];

    const int row = blockIdx.x;
    const int t   = threadIdx.x;
    const int lane = t & 63;
    const int wv   = t >> 6;
    const int n   = nnzArr[row];
    const int* rc = cols + (size_t)row * MAXNNZ;
    const float fsi = fs[row];

    float lm = -1e30f;
    for (int j = t; j < n; j += 256) {
        int c = rc[j];
        ci[j] = c;
        float e = fsi + fd[c];
        e = (e >= 0.0f) ? e : 0.2f * e;
        p[j] = e;
        lm = fmaxf(lm, e);
    }
#pragma unroll
    for (int off = 32; off; off >>= 1) lm = fmaxf(lm, __shfl_down(lm, off));
    if (lane == 0) red[wv] = lm;
    __syncthreads();
    const float m = fmaxf(fmaxf(red[0], red[1]), fmaxf(red[2], red[3]));
    __syncthreads();

    float ls = 0.0f;
    for (int j = t; j < n; j += 256) {
        float pe = expf(p[j] - m);
        p[j] = pe;
        ls += pe;
    }
#pragma unroll
    for (int off = 32; off; off >>= 1) ls += __shfl_down(ls, off);
    if (lane == 0) red[wv] = ls;
    __syncthreads();
    const float invZ = 1.0f / (red[0] + red[1] + red[2] + red[3]);

    const int d = t;
    float acc = 0.0f;
    int j = 0;
    for (; j + 4 <= n; j += 4) {
        float p0 = p[j], p1 = p[j + 1], p2 = p[j + 2], p3 = p[j + 3];
        int   c0 = ci[j], c1 = ci[j + 1], c2 = ci[j + 2], c3 = ci[j + 3];
        acc = fmaf(p0, Wh[(size_t)c0 * DE + d], acc);
        acc = fmaf(p1, Wh[(size_t)c1 * DE + d], acc);
        acc = fmaf(p2, Wh[(size_t)c2 * DE + d], acc);
        acc = fmaf(p3, Wh[(size_t)c3 * DE + d], acc);
    }
    for (; j < n; ++j) acc = fmaf(p[j], Wh[(size_t)ci[j] * DE + d], acc);
    acc *= invZ;

    float r;
    if (ACT == 0) r = (acc > 0.0f) ? acc : expm1f(acc);
    else          r = (acc > 0.0f) ? acc : 0.0f;
    out[(size_t)row * DE + d] = r;
}

// ---------------- launch ----------------
extern "C" void kernel_launch(void* const* d_in, const int* in_sizes, int n_in,
                              void* d_out, int out_size, void* d_ws, size_t ws_size,
                              hipStream_t stream)
{
    const float* x   = (const float*)d_in[0];
    const float* adj = (const float*)d_in[1];
    const float* W11 = (const float*)d_in[2];
    const float* a11 = (const float*)d_in[3];
    const float* W12 = (const float*)d_in[4];
    const float* a12 = (const float*)d_in[5];
    const float* W21 = (const float*)d_in[6];
    const float* a21 = (const float*)d_in[7];
    const float* W22 = (const float*)d_in[8];
    const float* a22 = (const float*)d_in[9];
    float* out = (float*)d_out;

    char* ws = (char*)d_ws;
    size_t off = 0;
    int*   cols = (int*)(ws + off);            off += (size_t)NV * MAXNNZ * 4;  // 3 MB
    int*   nnz  = (int*)(ws + off);            off += 16 * 1024;
    float* fs   = (float*)(ws + off);          off += 16 * 1024;
    float* fd   = (float*)(ws + off);          off += 16 * 1024;
    float* Wh   = (float*)(ws + off);          off += (size_t)NV * DE * 4;      // 4 MB
    float* hA   = (float*)(ws + off);          off += (size_t)NV * DE * 4;      // 4 MB
    unsigned short* BtH = (unsigned short*)(ws + off); off += (size_t)DE * NV * 2; // 2 MB
    unsigned short* BtL = (unsigned short*)(ws + off); off += (size_t)DE * NV * 2; // 2 MB
    float* Cpart = (float*)(ws + off);         // 8 MB (2 x NV x DE f32)

    build_csr<<<NV / 4, 256, 0, stream>>>(adj, cols, nnz);

    // ---- GAT1 layer 1 (K = 4096, split-K = 2) ----
    transp_split<<<dim3(NV / 32, DE / 32), 256, 0, stream>>>(W11, BtH, BtL, NV);
    gemm_split<<<dim3(DE / BN, NV / BM, 2), 256, 0, stream>>>(x, BtH, BtL, Cpart, NV, NV / 2);
    reduce_fsd<<<NV / 4, 256, 0, stream>>>(Cpart, a11, Wh, fs, fd);
    attn_spmm<0><<<NV, 256, 0, stream>>>(Wh, fs, fd, cols, nnz, hA);

    // ---- GAT1 layer 2 + fused ReLU (relu(elu(z)) == relu(z)) ----
    transp_split<<<dim3(DE / 32, DE / 32), 256, 0, stream>>>(W12, BtH, BtL, DE);
    gemm_split<<<dim3(DE / BN, NV / BM, 1), 256, 0, stream>>>(hA, BtH, BtL, Wh, DE, DE);
    fsd_kernel<<<NV / 4, 256, 0, stream>>>(Wh, a12, fs, fd);
    attn_spmm<1><<<NV, 256, 0, stream>>>(Wh, fs, fd, cols, nnz, hA);

    // ---- GAT2 layer 1 ----
    transp_split<<<dim3(DE / 32, DE / 32), 256, 0, stream>>>(W21, BtH, BtL, DE);
    gemm_split<<<dim3(DE / BN, NV / BM, 1), 256, 0, stream>>>(hA, BtH, BtL, Wh, DE, DE);
    fsd_kernel<<<NV / 4, 256, 0, stream>>>(Wh, a21, fs, fd);
    attn_spmm<0><<<NV, 256, 0, stream>>>(Wh, fs, fd, cols, nnz, hA);

    // ---- GAT2 layer 2 -> output ----
    transp_split<<<dim3(DE / 32, DE / 32), 256, 0, stream>>>(W22, BtH, BtL, DE);
    gemm_split<<<dim3(DE / BN, NV / BM, 1), 256, 0, stream>>>(hA, BtH, BtL, Wh, DE, DE);
    fsd_kernel<<<NV / 4, 256, 0, stream>>>(Wh, a22, fs, fd);
    attn_spmm<0><<<NV, 256, 0, stream>>>(Wh, fs, fd, cols, nnz, out);
}

// Round 3
// 194.089 us; speedup vs baseline: 1.9686x; 1.1762x over previous
//
#include <hip/hip_runtime.h>
#include <hip/hip_bf16.h>
#include <cstdint>
#include <cstddef>

#define NV 4096
#define DE 256
#define MAXNNZ 192

typedef __attribute__((ext_vector_type(8))) short bf16x8;
typedef __attribute__((ext_vector_type(4))) float f32x4;

__device__ __forceinline__ unsigned short f2bf(float f) {
    unsigned int u = __float_as_uint(f);
    u += 0x7fff + ((u >> 16) & 1);           // round-to-nearest-even
    return (unsigned short)(u >> 16);
}
__device__ __forceinline__ float bf2f(unsigned short h) {
    return __uint_as_float(((unsigned int)h) << 16);
}

// ---------------- CSR build: one wave per row, ballot-compact ----------------
__global__ __launch_bounds__(256) void build_csr(const float* __restrict__ adj,
                                                 int* __restrict__ cols,
                                                 int* __restrict__ nnz)
{
    int wave = threadIdx.x >> 6;
    int lane = threadIdx.x & 63;
    int row  = blockIdx.x * 4 + wave;
    const float* arow = adj + (size_t)row * NV;
    int* crow = cols + (size_t)row * MAXNNZ;
    int base = 0;
    for (int c0 = 0; c0 < NV; c0 += 64) {
        float v = arow[c0 + lane];
        bool pred = v > 0.0f;
        unsigned long long m = __ballot(pred);
        int idx = base + __popcll(m & ((1ull << lane) - 1ull));
        if (pred && idx < MAXNNZ) crow[idx] = c0 + lane;
        base += __popcll(m);
    }
    if (lane == 0) nnz[row] = base < MAXNNZ ? base : MAXNNZ;
}

// ------------- W transpose + bf16 hi/lo split: [K][256] f32 -> [256][K] -------------
__global__ __launch_bounds__(256) void transp_split(const float* __restrict__ W,
                                                    unsigned short* __restrict__ bh,
                                                    unsigned short* __restrict__ bl,
                                                    int K)
{
    __shared__ float tile[32][33];
    const int k0 = blockIdx.x * 32, n0 = blockIdx.y * 32;
    const int t = threadIdx.x;
    {
        int r = t >> 3, cq = t & 7;
        float4 v = *(const float4*)&W[(size_t)(k0 + r) * DE + n0 + cq * 4];
        tile[r][cq * 4 + 0] = v.x;
        tile[r][cq * 4 + 1] = v.y;
        tile[r][cq * 4 + 2] = v.z;
        tile[r][cq * 4 + 3] = v.w;
    }
    __syncthreads();
    {
        int nl = t >> 3, kq = t & 7;
        ushort4 hv, lv;
        float x0 = tile[kq * 4 + 0][nl];
        float x1 = tile[kq * 4 + 1][nl];
        float x2 = tile[kq * 4 + 2][nl];
        float x3 = tile[kq * 4 + 3][nl];
        hv.x = f2bf(x0); lv.x = f2bf(x0 - bf2f(hv.x));
        hv.y = f2bf(x1); lv.y = f2bf(x1 - bf2f(hv.y));
        hv.z = f2bf(x2); lv.z = f2bf(x2 - bf2f(hv.z));
        hv.w = f2bf(x3); lv.w = f2bf(x3 - bf2f(hv.w));
        size_t o = (size_t)(n0 + nl) * K + k0 + kq * 4;
        *(ushort4*)&bh[o] = hv;
        *(ushort4*)&bl[o] = lv;
    }
}

// ---------------- split-bf16 MFMA GEMM ----------------
// Block tile 64x64, BK=32, 4 waves (2x2) each owning a 32x32 sub-tile.
// LDS per matrix: [row][64] u16; chunks(8 u16) 0..3 = hi, 4..7 = lo,
// chunk index XOR-swizzled with (row&7).
#define BM 64
#define BN 64
#define BK 32

__global__ __launch_bounds__(256) void gemm_split(const float* __restrict__ A,
                                                  const unsigned short* __restrict__ Bh,
                                                  const unsigned short* __restrict__ Bl,
                                                  float* __restrict__ C,
                                                  int K, int Kchunk)
{
    __shared__ __align__(16) unsigned short sA[64 * 64];
    __shared__ __align__(16) unsigned short sB[64 * 64];

    const int t    = threadIdx.x;
    const int lane = t & 63;
    const int wid  = t >> 6;
    const int wr   = wid >> 1;      // 0..1
    const int wc   = wid & 1;       // 0..1
    const int bn   = blockIdx.x * BN;
    const int bm   = blockIdx.y * BM;
    const int kz   = blockIdx.z;
    const int kbeg = kz * Kchunk;
    const int nsteps = Kchunk / BK;

    // staging maps
    const int ar = t >> 2;               // 0..63  (A tile row)
    const int as = t & 3;                // A k-chunk (8 f32)
    const int br = t >> 2;               // 0..63  (B tile row = output col)
    const int bq = t & 3;                // B k-chunk (8 bf16)

    const float*          Ap  = A  + (size_t)(bm + ar) * K + kbeg + as * 8;
    const unsigned short* Bhp = Bh + (size_t)(bn + br) * K + kbeg + bq * 8;
    const unsigned short* Blp = Bl + (size_t)(bn + br) * K + kbeg + bq * 8;

    // LDS write offsets (u16 units)
    const int aw_h = ar * 64 + (((as)      ^ (ar & 7)) << 3);
    const int aw_l = ar * 64 + (((as | 4)  ^ (ar & 7)) << 3);
    const int bw_h = br * 64 + (((bq)      ^ (br & 7)) << 3);
    const int bw_l = br * 64 + (((bq | 4)  ^ (br & 7)) << 3);

    // frag read offsets
    const int fr = lane & 15, fsub = lane >> 4;
    const int arow0 = wr * 32 + fr;
    const int arow1 = arow0 + 16;
    const int ard0h = arow0 * 64 + (((fsub)     ^ (arow0 & 7)) << 3);
    const int ard0l = arow0 * 64 + (((fsub | 4) ^ (arow0 & 7)) << 3);
    const int ard1h = arow1 * 64 + (((fsub)     ^ (arow1 & 7)) << 3);
    const int ard1l = arow1 * 64 + (((fsub | 4) ^ (arow1 & 7)) << 3);
    const int brow0 = wc * 32 + fr;
    const int brow1 = brow0 + 16;
    const int brd0h = brow0 * 64 + (((fsub)     ^ (brow0 & 7)) << 3);
    const int brd0l = brow0 * 64 + (((fsub | 4) ^ (brow0 & 7)) << 3);
    const int brd1h = brow1 * 64 + (((fsub)     ^ (brow1 & 7)) << 3);
    const int brd1l = brow1 * 64 + (((fsub | 4) ^ (brow1 & 7)) << 3);

    // prologue loads
    float4 a0 = *(const float4*)(Ap);
    float4 a1 = *(const float4*)(Ap + 4);
    bf16x8 g_bh = *(const bf16x8*)(Bhp);
    bf16x8 g_bl = *(const bf16x8*)(Blp);

    f32x4 acc[2][2];
#pragma unroll
    for (int i = 0; i < 2; ++i)
#pragma unroll
        for (int j = 0; j < 2; ++j) acc[i][j] = (f32x4){0.f, 0.f, 0.f, 0.f};

    for (int s = 0; s < nsteps; ++s) {
        __syncthreads();   // previous step's LDS readers done
        {   // convert + store A
            float xs0 = a0.x, xs1 = a0.y, xs2 = a0.z, xs3 = a0.w;
            float xs4 = a1.x, xs5 = a1.y, xs6 = a1.z, xs7 = a1.w;
            bf16x8 hv, lv;
            unsigned short h;
            h = f2bf(xs0); hv[0] = (short)h; lv[0] = (short)f2bf(xs0 - bf2f(h));
            h = f2bf(xs1); hv[1] = (short)h; lv[1] = (short)f2bf(xs1 - bf2f(h));
            h = f2bf(xs2); hv[2] = (short)h; lv[2] = (short)f2bf(xs2 - bf2f(h));
            h = f2bf(xs3); hv[3] = (short)h; lv[3] = (short)f2bf(xs3 - bf2f(h));
            h = f2bf(xs4); hv[4] = (short)h; lv[4] = (short)f2bf(xs4 - bf2f(h));
            h = f2bf(xs5); hv[5] = (short)h; lv[5] = (short)f2bf(xs5 - bf2f(h));
            h = f2bf(xs6); hv[6] = (short)h; lv[6] = (short)f2bf(xs6 - bf2f(h));
            h = f2bf(xs7); hv[7] = (short)h; lv[7] = (short)f2bf(xs7 - bf2f(h));
            *(bf16x8*)&sA[aw_h] = hv;
            *(bf16x8*)&sA[aw_l] = lv;
        }
        *(bf16x8*)&sB[bw_h] = g_bh;
        *(bf16x8*)&sB[bw_l] = g_bl;
        __syncthreads();

        if (s + 1 < nsteps) {   // prefetch next tile (hidden under MFMA)
            Ap += BK; Bhp += BK; Blp += BK;
            a0 = *(const float4*)(Ap);
            a1 = *(const float4*)(Ap + 4);
            g_bh = *(const bf16x8*)(Bhp);
            g_bl = *(const bf16x8*)(Blp);
        }

        bf16x8 ah0 = *(const bf16x8*)&sA[ard0h];
        bf16x8 al0 = *(const bf16x8*)&sA[ard0l];
        bf16x8 ah1 = *(const bf16x8*)&sA[ard1h];
        bf16x8 al1 = *(const bf16x8*)&sA[ard1l];
        bf16x8 bh0 = *(const bf16x8*)&sB[brd0h];
        bf16x8 bl0 = *(const bf16x8*)&sB[brd0l];
        bf16x8 bh1 = *(const bf16x8*)&sB[brd1h];
        bf16x8 bl1 = *(const bf16x8*)&sB[brd1l];

        acc[0][0] = __builtin_amdgcn_mfma_f32_16x16x32_bf16(ah0, bh0, acc[0][0], 0, 0, 0);
        acc[0][0] = __builtin_amdgcn_mfma_f32_16x16x32_bf16(ah0, bl0, acc[0][0], 0, 0, 0);
        acc[0][0] = __builtin_amdgcn_mfma_f32_16x16x32_bf16(al0, bh0, acc[0][0], 0, 0, 0);
        acc[0][1] = __builtin_amdgcn_mfma_f32_16x16x32_bf16(ah0, bh1, acc[0][1], 0, 0, 0);
        acc[0][1] = __builtin_amdgcn_mfma_f32_16x16x32_bf16(ah0, bl1, acc[0][1], 0, 0, 0);
        acc[0][1] = __builtin_amdgcn_mfma_f32_16x16x32_bf16(al0, bh1, acc[0][1], 0, 0, 0);
        acc[1][0] = __builtin_amdgcn_mfma_f32_16x16x32_bf16(ah1, bh0, acc[1][0], 0, 0, 0);
        acc[1][0] = __builtin_amdgcn_mfma_f32_16x16x32_bf16(ah1, bl0, acc[1][0], 0, 0, 0);
        acc[1][0] = __builtin_amdgcn_mfma_f32_16x16x32_bf16(al1, bh0, acc[1][0], 0, 0, 0);
        acc[1][1] = __builtin_amdgcn_mfma_f32_16x16x32_bf16(ah1, bh1, acc[1][1], 0, 0, 0);
        acc[1][1] = __builtin_amdgcn_mfma_f32_16x16x32_bf16(ah1, bl1, acc[1][1], 0, 0, 0);
        acc[1][1] = __builtin_amdgcn_mfma_f32_16x16x32_bf16(al1, bh1, acc[1][1], 0, 0, 0);
    }

    // epilogue: C/D layout: col = lane&15, row = (lane>>4)*4 + reg
    float* Cb = C + (size_t)kz * NV * DE;
#pragma unroll
    for (int mi = 0; mi < 2; ++mi) {
#pragma unroll
        for (int ni = 0; ni < 2; ++ni) {
            int row = bm + wr * 32 + mi * 16 + (fsub << 2);
            int col = bn + wc * 32 + ni * 16 + fr;
#pragma unroll
            for (int i = 0; i < 4; ++i)
                Cb[(size_t)(row + i) * DE + col] = acc[mi][ni][i];
        }
    }
}

// ---------------- split-K reduce + f_src/f_dst ----------------
__global__ __launch_bounds__(256) void reduce_fsd(const float* __restrict__ Cp,
                                                  const float* __restrict__ a,
                                                  float* __restrict__ Wh,
                                                  float* __restrict__ fs,
                                                  float* __restrict__ fd,
                                                  int S)
{
    int wid = threadIdx.x >> 6, lane = threadIdx.x & 63;
    int row = blockIdx.x * 4 + wid;
    size_t idx = (size_t)row * DE + lane * 4;
    float4 w = *(const float4*)&Cp[idx];
    for (int s = 1; s < S; ++s) {
        float4 p = *(const float4*)&Cp[(size_t)s * NV * DE + idx];
        w.x += p.x; w.y += p.y; w.z += p.z; w.w += p.w;
    }
    *(float4*)&Wh[idx] = w;
    float4 at = *(const float4*)&a[lane * 4];
    float4 ab = *(const float4*)&a[DE + lane * 4];
    float s = w.x * at.x + w.y * at.y + w.z * at.z + w.w * at.w;
    float d = w.x * ab.x + w.y * ab.y + w.z * ab.z + w.w * ab.w;
#pragma unroll
    for (int off = 32; off; off >>= 1) {
        s += __shfl_down(s, off);
        d += __shfl_down(d, off);
    }
    if (lane == 0) { fs[row] = s; fd[row] = d; }
}

// ---------------- fused masked-softmax + SpMM + activation ----------------
template <int ACT>   // 0 = ELU, 1 = ReLU
__global__ __launch_bounds__(256) void attn_spmm(const float* __restrict__ Wh,
                                                 const float* __restrict__ fs,
                                                 const float* __restrict__ fd,
                                                 const int* __restrict__ cols,
                                                 const int* __restrict__ nnzArr,
                                                 float* __restrict__ out)
{
    __shared__ float p[MAXNNZ];
    __shared__ int   ci[MAXNNZ];
    __shared__ float red[4];
    __shared__ float part[4][DE];

    const int row = blockIdx.x;
    const int t   = threadIdx.x;
    const int lane = t & 63;
    const int wv   = t >> 6;
    const int n   = nnzArr[row];
    const int* rc = cols + (size_t)row * MAXNNZ;
    const float fsi = fs[row];

    // phase 1: e = leakyrelu(fs_i + fd_j), row max
    float lm = -1e30f;
    for (int j = t; j < n; j += 256) {
        int c = rc[j];
        ci[j] = c;
        float e = fsi + fd[c];
        e = (e >= 0.0f) ? e : 0.2f * e;
        p[j] = e;
        lm = fmaxf(lm, e);
    }
#pragma unroll
    for (int off = 32; off; off >>= 1) lm = fmaxf(lm, __shfl_down(lm, off));
    if (lane == 0) red[wv] = lm;
    __syncthreads();
    const float m = fmaxf(fmaxf(red[0], red[1]), fmaxf(red[2], red[3]));
    __syncthreads();

    // phase 2: exp + sum
    float ls = 0.0f;
    for (int j = t; j < n; j += 256) {
        float pe = expf(p[j] - m);
        p[j] = pe;
        ls += pe;
    }
#pragma unroll
    for (int off = 32; off; off >>= 1) ls += __shfl_down(ls, off);
    if (lane == 0) red[wv] = ls;
    __syncthreads();
    const float invZ = 1.0f / (red[0] + red[1] + red[2] + red[3]);

    // phase 3: wave-parallel over j, lane-parallel (float4) over d
    const int d4 = lane * 4;
    f32x4 acc = (f32x4){0.f, 0.f, 0.f, 0.f};
    int j = wv;
    for (; j + 4 < n; j += 8) {
        float pj0 = p[j];     int c0 = ci[j];
        float pj1 = p[j + 4]; int c1 = ci[j + 4];
        float4 w0 = *(const float4*)&Wh[(size_t)c0 * DE + d4];
        float4 w1 = *(const float4*)&Wh[(size_t)c1 * DE + d4];
        acc.x = fmaf(pj0, w0.x, acc.x);
        acc.y = fmaf(pj0, w0.y, acc.y);
        acc.z = fmaf(pj0, w0.z, acc.z);
        acc.w = fmaf(pj0, w0.w, acc.w);
        acc.x = fmaf(pj1, w1.x, acc.x);
        acc.y = fmaf(pj1, w1.y, acc.y);
        acc.z = fmaf(pj1, w1.z, acc.z);
        acc.w = fmaf(pj1, w1.w, acc.w);
    }
    for (; j < n; j += 4) {
        float pj = p[j]; int c = ci[j];
        float4 w0 = *(const float4*)&Wh[(size_t)c * DE + d4];
        acc.x = fmaf(pj, w0.x, acc.x);
        acc.y = fmaf(pj, w0.y, acc.y);
        acc.z = fmaf(pj, w0.z, acc.z);
        acc.w = fmaf(pj, w0.w, acc.w);
    }
    *(f32x4*)&part[wv][d4] = acc;
    __syncthreads();

    float v = (part[0][t] + part[1][t]) + (part[2][t] + part[3][t]);
    v *= invZ;
    float r;
    if (ACT == 0) r = (v > 0.0f) ? v : expm1f(v);
    else          r = (v > 0.0f) ? v : 0.0f;
    out[(size_t)row * DE + t] = r;
}

// ---------------- launch ----------------
extern "C" void kernel_launch(void* const* d_in, const int* in_sizes, int n_in,
                              void* d_out, int out_size, void* d_ws, size_t ws_size,
                              hipStream_t stream)
{
    const float* x   = (const float*)d_in[0];
    const float* adj = (const float*)d_in[1];
    const float* W11 = (const float*)d_in[2];
    const float* a11 = (const float*)d_in[3];
    const float* W12 = (const float*)d_in[4];
    const float* a12 = (const float*)d_in[5];
    const float* W21 = (const float*)d_in[6];
    const float* a21 = (const float*)d_in[7];
    const float* W22 = (const float*)d_in[8];
    const float* a22 = (const float*)d_in[9];
    float* out = (float*)d_out;

    char* ws = (char*)d_ws;
    size_t off = 0;
    int*   cols = (int*)(ws + off);            off += (size_t)NV * MAXNNZ * 4;  // 3 MB
    int*   nnz  = (int*)(ws + off);            off += 16 * 1024;
    float* fs   = (float*)(ws + off);          off += 16 * 1024;
    float* fd   = (float*)(ws + off);          off += 16 * 1024;
    float* Wh   = (float*)(ws + off);          off += (size_t)NV * DE * 4;      // 4 MB
    float* hA   = (float*)(ws + off);          off += (size_t)NV * DE * 4;      // 4 MB
    unsigned short* BtH = (unsigned short*)(ws + off); off += (size_t)DE * NV * 2; // 2 MB
    unsigned short* BtL = (unsigned short*)(ws + off); off += (size_t)DE * NV * 2; // 2 MB
    float* Cpart = (float*)(ws + off);         // 16 MB (4 x NV x DE f32)

    build_csr<<<NV / 4, 256, 0, stream>>>(adj, cols, nnz);

    // ---- GAT1 layer 1 (K = 4096, split-K = 4) ----
    transp_split<<<dim3(NV / 32, DE / 32), 256, 0, stream>>>(W11, BtH, BtL, NV);
    gemm_split<<<dim3(DE / BN, NV / BM, 4), 256, 0, stream>>>(x, BtH, BtL, Cpart, NV, NV / 4);
    reduce_fsd<<<NV / 4, 256, 0, stream>>>(Cpart, a11, Wh, fs, fd, 4);
    attn_spmm<0><<<NV, 256, 0, stream>>>(Wh, fs, fd, cols, nnz, hA);

    // ---- GAT1 layer 2 + fused ReLU (relu(elu(z)) == relu(z)) ----
    transp_split<<<dim3(DE / 32, DE / 32), 256, 0, stream>>>(W12, BtH, BtL, DE);
    gemm_split<<<dim3(DE / BN, NV / BM, 2), 256, 0, stream>>>(hA, BtH, BtL, Cpart, DE, DE / 2);
    reduce_fsd<<<NV / 4, 256, 0, stream>>>(Cpart, a12, Wh, fs, fd, 2);
    attn_spmm<1><<<NV, 256, 0, stream>>>(Wh, fs, fd, cols, nnz, hA);

    // ---- GAT2 layer 1 ----
    transp_split<<<dim3(DE / 32, DE / 32), 256, 0, stream>>>(W21, BtH, BtL, DE);
    gemm_split<<<dim3(DE / BN, NV / BM, 2), 256, 0, stream>>>(hA, BtH, BtL, Cpart, DE, DE / 2);
    reduce_fsd<<<NV / 4, 256, 0, stream>>>(Cpart, a21, Wh, fs, fd, 2);
    attn_spmm<0><<<NV, 256, 0, stream>>>(Wh, fs, fd, cols, nnz, hA);

    // ---- GAT2 layer 2 -> output ----
    transp_split<<<dim3(DE / 32, DE / 32), 256, 0, stream>>>(W22, BtH, BtL, DE);
    gemm_split<<<dim3(DE / BN, NV / BM, 2), 256, 0, stream>>>(hA, BtH, BtL, Cpart, DE, DE / 2);
    reduce_fsd<<<NV / 4, 256, 0, stream>>>(Cpart, a22, Wh, fs, fd, 2);
    attn_spmm<0><<<NV, 256, 0, stream>>>(Wh, fs, fd, cols, nnz, out);
}

// Round 4
// 184.517 us; speedup vs baseline: 2.0707x; 1.0519x over previous
//
#include <hip/hip_runtime.h>
#include <hip/hip_bf16.h>
#include <cstdint>
#include <cstddef>

#define NV 4096
#define DE 256
#define MAXNNZ 192

typedef __attribute__((ext_vector_type(8))) short bf16x8;
typedef __attribute__((ext_vector_type(4))) float f32x4;

__device__ __forceinline__ unsigned short f2bf(float f) {
    unsigned int u = __float_as_uint(f);
    u += 0x7fff + ((u >> 16) & 1);           // RNE
    return (unsigned short)(u >> 16);
}
__device__ __forceinline__ float bf2f(unsigned short h) {
    return __uint_as_float(((unsigned int)h) << 16);
}

// ---------------- CSR build: one wave per row, float4 + ballot-compact ----------------
__global__ __launch_bounds__(256) void build_csr(const float* __restrict__ adj,
                                                 int* __restrict__ cols,
                                                 int* __restrict__ nnz)
{
    int wave = threadIdx.x >> 6;
    int lane = threadIdx.x & 63;
    int row  = blockIdx.x * 4 + wave;
    const float* arow = adj + (size_t)row * NV;
    int* crow = cols + (size_t)row * MAXNNZ;
    int base = 0;
    for (int c0 = 0; c0 < NV; c0 += 256) {
        float4 v = *(const float4*)&arow[c0 + lane * 4];
        float vv[4] = {v.x, v.y, v.z, v.w};
#pragma unroll
        for (int e = 0; e < 4; ++e) {
            bool pred = vv[e] > 0.0f;
            unsigned long long m = __ballot(pred);
            int idx = base + __popcll(m & ((1ull << lane) - 1ull));
            if (pred && idx < MAXNNZ) crow[idx] = c0 + lane * 4 + e;
            base += __popcll(m);
        }
    }
    if (lane == 0) nnz[row] = base < MAXNNZ ? base : MAXNNZ;
}

// ------------- W transpose + bf16 hi/lo split: [K][256] f32 -> [256][K] -------------
__global__ __launch_bounds__(256) void transp_split(const float* __restrict__ W,
                                                    unsigned short* __restrict__ bh,
                                                    unsigned short* __restrict__ bl,
                                                    int K)
{
    __shared__ float tile[32][33];
    const int k0 = blockIdx.x * 32, n0 = blockIdx.y * 32;
    const int t = threadIdx.x;
    {
        int r = t >> 3, cq = t & 7;
        float4 v = *(const float4*)&W[(size_t)(k0 + r) * DE + n0 + cq * 4];
        tile[r][cq * 4 + 0] = v.x;
        tile[r][cq * 4 + 1] = v.y;
        tile[r][cq * 4 + 2] = v.z;
        tile[r][cq * 4 + 3] = v.w;
    }
    __syncthreads();
    {
        int nl = t >> 3, kq = t & 7;
        ushort4 hv, lv;
        float x0 = tile[kq * 4 + 0][nl];
        float x1 = tile[kq * 4 + 1][nl];
        float x2 = tile[kq * 4 + 2][nl];
        float x3 = tile[kq * 4 + 3][nl];
        hv.x = f2bf(x0); lv.x = f2bf(x0 - bf2f(hv.x));
        hv.y = f2bf(x1); lv.y = f2bf(x1 - bf2f(hv.y));
        hv.z = f2bf(x2); lv.z = f2bf(x2 - bf2f(hv.z));
        hv.w = f2bf(x3); lv.w = f2bf(x3 - bf2f(hv.w));
        size_t o = (size_t)(n0 + nl) * K + k0 + kq * 4;
        *(ushort4*)&bh[o] = hv;
        *(ushort4*)&bl[o] = lv;
    }
}

// ---------------- split-bf16 MFMA GEMM, 128x128 tile ----------------
// 4 waves (2x2), wave tile 64x64, BK=32. 16 ds_read_b128 -> 48 MFMA per wave-step.
// LDS [row][64] u16: chunks(8 u16) 0..3 = hi(k 0..31), 4..7 = lo; chunk ^= (row&7).
// 1D grid, bijective XCD swizzle; wgid = (col*KZ + kz)*32 + row_tile.
template <bool PRESPLIT>
__global__ __launch_bounds__(256, 2) void gemm_bt(const float* __restrict__ Af,
                                                  const unsigned short* __restrict__ Ah,
                                                  const unsigned short* __restrict__ Al,
                                                  const unsigned short* __restrict__ Bh,
                                                  const unsigned short* __restrict__ Bl,
                                                  float* __restrict__ C,
                                                  int K, int Kchunk)
{
    __shared__ __align__(16) unsigned short sA[128 * 64];
    __shared__ __align__(16) unsigned short sB[128 * 64];

    const int t = threadIdx.x, lane = t & 63, wid = t >> 6;
    const int wr = wid >> 1, wc = wid & 1;
    const int KZ = K / Kchunk;

    // bijective XCD swizzle (m204)
    const int nwg = gridDim.x, orig = blockIdx.x;
    const int q = nwg >> 3, r = nwg & 7;
    const int xcd = orig & 7, jj = orig >> 3;
    const int wgid = (xcd < r ? xcd * (q + 1) : r * (q + 1) + (xcd - r) * q) + jj;
    const int row_t = wgid & 31;
    const int kz    = (wgid >> 5) % KZ;
    const int colt  = wgid / (32 * KZ);
    const int bm = row_t * 128, bn = colt * 128;
    const int kbeg = kz * Kchunk;
    const int nsteps = Kchunk / 32;

    // staging: row = t>>1 (0..127), half = t&1 (k 0..15 / 16..31)
    const int srow = t >> 1, shalf = t & 1;
    const float*          Afp = Af ? (Af + (size_t)(bm + srow) * K + kbeg + shalf * 16) : nullptr;
    const unsigned short* Ahp = Ah ? (Ah + (size_t)(bm + srow) * K + kbeg + shalf * 16) : nullptr;
    const unsigned short* Alp = Al ? (Al + (size_t)(bm + srow) * K + kbeg + shalf * 16) : nullptr;
    const unsigned short* Bhp = Bh + (size_t)(bn + srow) * K + kbeg + shalf * 16;
    const unsigned short* Blp = Bl + (size_t)(bn + srow) * K + kbeg + shalf * 16;

    const int c0 = shalf * 2;
    const int wa0 = srow * 64 + (((c0)           ^ (srow & 7)) << 3);
    const int wa1 = srow * 64 + (((c0 + 1)       ^ (srow & 7)) << 3);
    const int wa2 = srow * 64 + (((c0 | 4)       ^ (srow & 7)) << 3);
    const int wa3 = srow * 64 + ((((c0 + 1) | 4) ^ (srow & 7)) << 3);

    const int fr = lane & 15, fsub = lane >> 4;

    bf16x8 gah0, gah1, gal0, gal1, gbh0, gbh1, gbl0, gbl1;

#define LOAD_TILE()                                                          \
    do {                                                                     \
        if (PRESPLIT) {                                                      \
            gah0 = *(const bf16x8*)(Ahp);                                    \
            gah1 = *(const bf16x8*)(Ahp + 8);                                \
            gal0 = *(const bf16x8*)(Alp);                                    \
            gal1 = *(const bf16x8*)(Alp + 8);                                \
        } else {                                                             \
            float4 f0 = *(const float4*)(Afp);                               \
            float4 f1 = *(const float4*)(Afp + 4);                           \
            float4 f2 = *(const float4*)(Afp + 8);                           \
            float4 f3 = *(const float4*)(Afp + 12);                          \
            float xs[16] = {f0.x, f0.y, f0.z, f0.w, f1.x, f1.y, f1.z, f1.w,  \
                            f2.x, f2.y, f2.z, f2.w, f3.x, f3.y, f3.z, f3.w}; \
            _Pragma("unroll") for (int e = 0; e < 8; ++e) {                  \
                unsigned short h = f2bf(xs[e]);                              \
                gah0[e] = (short)h;                                          \
                gal0[e] = (short)f2bf(xs[e] - bf2f(h));                      \
            }                                                                \
            _Pragma("unroll") for (int e = 0; e < 8; ++e) {                  \
                unsigned short h = f2bf(xs[8 + e]);                          \
                gah1[e] = (short)h;                                          \
                gal1[e] = (short)f2bf(xs[8 + e] - bf2f(h));                  \
            }                                                                \
        }                                                                    \
        gbh0 = *(const bf16x8*)(Bhp);                                        \
        gbh1 = *(const bf16x8*)(Bhp + 8);                                    \
        gbl0 = *(const bf16x8*)(Blp);                                        \
        gbl1 = *(const bf16x8*)(Blp + 8);                                    \
    } while (0)

    LOAD_TILE();

    f32x4 acc[4][4];
#pragma unroll
    for (int i = 0; i < 4; ++i)
#pragma unroll
        for (int j2 = 0; j2 < 4; ++j2) acc[i][j2] = (f32x4){0.f, 0.f, 0.f, 0.f};

    for (int s = 0; s < nsteps; ++s) {
        __syncthreads();
        *(bf16x8*)&sA[wa0] = gah0;
        *(bf16x8*)&sA[wa1] = gah1;
        *(bf16x8*)&sA[wa2] = gal0;
        *(bf16x8*)&sA[wa3] = gal1;
        *(bf16x8*)&sB[wa0] = gbh0;
        *(bf16x8*)&sB[wa1] = gbh1;
        *(bf16x8*)&sB[wa2] = gbl0;
        *(bf16x8*)&sB[wa3] = gbl1;
        __syncthreads();

        if (s + 1 < nsteps) {
            if (PRESPLIT) { Ahp += 32; Alp += 32; }
            else          { Afp += 32; }
            Bhp += 32; Blp += 32;
            LOAD_TILE();
        }

        bf16x8 fah[4], fal[4], fbh[4], fbl[4];
#pragma unroll
        for (int mi = 0; mi < 4; ++mi) {
            int row = wr * 64 + mi * 16 + fr;
            fah[mi] = *(const bf16x8*)&sA[row * 64 + (((fsub)     ^ (row & 7)) << 3)];
            fal[mi] = *(const bf16x8*)&sA[row * 64 + (((fsub | 4) ^ (row & 7)) << 3)];
        }
#pragma unroll
        for (int ni = 0; ni < 4; ++ni) {
            int row = wc * 64 + ni * 16 + fr;
            fbh[ni] = *(const bf16x8*)&sB[row * 64 + (((fsub)     ^ (row & 7)) << 3)];
            fbl[ni] = *(const bf16x8*)&sB[row * 64 + (((fsub | 4) ^ (row & 7)) << 3)];
        }
#pragma unroll
        for (int mi = 0; mi < 4; ++mi)
#pragma unroll
            for (int ni = 0; ni < 4; ++ni) {
                acc[mi][ni] = __builtin_amdgcn_mfma_f32_16x16x32_bf16(fah[mi], fbh[ni], acc[mi][ni], 0, 0, 0);
                acc[mi][ni] = __builtin_amdgcn_mfma_f32_16x16x32_bf16(fah[mi], fbl[ni], acc[mi][ni], 0, 0, 0);
                acc[mi][ni] = __builtin_amdgcn_mfma_f32_16x16x32_bf16(fal[mi], fbh[ni], acc[mi][ni], 0, 0, 0);
            }
    }
#undef LOAD_TILE

    // C/D layout: col = lane&15, row = (lane>>4)*4 + reg
    float* Cb = C + (size_t)kz * NV * DE;
#pragma unroll
    for (int mi = 0; mi < 4; ++mi) {
#pragma unroll
        for (int ni = 0; ni < 4; ++ni) {
            int row = bm + wr * 64 + mi * 16 + (fsub << 2);
            int col = bn + wc * 64 + ni * 16 + fr;
#pragma unroll
            for (int i = 0; i < 4; ++i)
                Cb[(size_t)(row + i) * DE + col] = acc[mi][ni][i];
        }
    }
}

// ---------------- split-K reduce + f_src/f_dst ----------------
__global__ __launch_bounds__(256) void reduce_fsd(const float* __restrict__ Cp,
                                                  const float* __restrict__ a,
                                                  float* __restrict__ Wh,
                                                  float* __restrict__ fs,
                                                  float* __restrict__ fd,
                                                  int S)
{
    int wid = threadIdx.x >> 6, lane = threadIdx.x & 63;
    int row = blockIdx.x * 4 + wid;
    size_t idx = (size_t)row * DE + lane * 4;
    float4 w = *(const float4*)&Cp[idx];
    for (int s = 1; s < S; ++s) {
        float4 p = *(const float4*)&Cp[(size_t)s * NV * DE + idx];
        w.x += p.x; w.y += p.y; w.z += p.z; w.w += p.w;
    }
    *(float4*)&Wh[idx] = w;
    float4 at = *(const float4*)&a[lane * 4];
    float4 ab = *(const float4*)&a[DE + lane * 4];
    float s = w.x * at.x + w.y * at.y + w.z * at.z + w.w * at.w;
    float d = w.x * ab.x + w.y * ab.y + w.z * ab.z + w.w * ab.w;
#pragma unroll
    for (int off = 32; off; off >>= 1) {
        s += __shfl_down(s, off);
        d += __shfl_down(d, off);
    }
    if (lane == 0) { fs[row] = s; fd[row] = d; }
}

// ---------------- fused masked-softmax + SpMM + activation ----------------
// ACT: 0 = ELU, 1 = ReLU.  SPLIT: write bf16 hi/lo h (for next GEMM) vs f32 out.
template <int ACT, bool SPLIT>
__global__ __launch_bounds__(256) void attn_spmm(const float* __restrict__ Wh,
                                                 const float* __restrict__ fs,
                                                 const float* __restrict__ fd,
                                                 const int* __restrict__ cols,
                                                 const int* __restrict__ nnzArr,
                                                 float* __restrict__ out,
                                                 unsigned short* __restrict__ hh,
                                                 unsigned short* __restrict__ hl)
{
    __shared__ float p[MAXNNZ];
    __shared__ int   ci[MAXNNZ];
    __shared__ float red[4];
    __shared__ float part[4][DE];

    const int row = blockIdx.x;
    const int t   = threadIdx.x;
    const int lane = t & 63;
    const int wv   = t >> 6;
    const int n   = nnzArr[row];
    const int* rc = cols + (size_t)row * MAXNNZ;
    const float fsi = fs[row];

    float lm = -1e30f;
    for (int j = t; j < n; j += 256) {
        int c = rc[j];
        ci[j] = c;
        float e = fsi + fd[c];
        e = (e >= 0.0f) ? e : 0.2f * e;
        p[j] = e;
        lm = fmaxf(lm, e);
    }
#pragma unroll
    for (int off = 32; off; off >>= 1) lm = fmaxf(lm, __shfl_down(lm, off));
    if (lane == 0) red[wv] = lm;
    __syncthreads();
    const float m = fmaxf(fmaxf(red[0], red[1]), fmaxf(red[2], red[3]));
    __syncthreads();

    float ls = 0.0f;
    for (int j = t; j < n; j += 256) {
        float pe = expf(p[j] - m);
        p[j] = pe;
        ls += pe;
    }
#pragma unroll
    for (int off = 32; off; off >>= 1) ls += __shfl_down(ls, off);
    if (lane == 0) red[wv] = ls;
    __syncthreads();
    const float invZ = 1.0f / (red[0] + red[1] + red[2] + red[3]);

    const int d4 = lane * 4;
    f32x4 acc = (f32x4){0.f, 0.f, 0.f, 0.f};
    int j = wv;
    for (; j + 4 < n; j += 8) {
        float pj0 = p[j];     int c0 = ci[j];
        float pj1 = p[j + 4]; int c1 = ci[j + 4];
        float4 w0 = *(const float4*)&Wh[(size_t)c0 * DE + d4];
        float4 w1 = *(const float4*)&Wh[(size_t)c1 * DE + d4];
        acc.x = fmaf(pj0, w0.x, acc.x);
        acc.y = fmaf(pj0, w0.y, acc.y);
        acc.z = fmaf(pj0, w0.z, acc.z);
        acc.w = fmaf(pj0, w0.w, acc.w);
        acc.x = fmaf(pj1, w1.x, acc.x);
        acc.y = fmaf(pj1, w1.y, acc.y);
        acc.z = fmaf(pj1, w1.z, acc.z);
        acc.w = fmaf(pj1, w1.w, acc.w);
    }
    for (; j < n; j += 4) {
        float pj = p[j]; int c = ci[j];
        float4 w0 = *(const float4*)&Wh[(size_t)c * DE + d4];
        acc.x = fmaf(pj, w0.x, acc.x);
        acc.y = fmaf(pj, w0.y, acc.y);
        acc.z = fmaf(pj, w0.z, acc.z);
        acc.w = fmaf(pj, w0.w, acc.w);
    }
    *(f32x4*)&part[wv][d4] = acc;
    __syncthreads();

    float v = (part[0][t] + part[1][t]) + (part[2][t] + part[3][t]);
    v *= invZ;
    float rres;
    if (ACT == 0) rres = (v > 0.0f) ? v : expm1f(v);
    else          rres = (v > 0.0f) ? v : 0.0f;

    if (SPLIT) {
        unsigned short h = f2bf(rres);
        hh[(size_t)row * DE + t] = h;
        hl[(size_t)row * DE + t] = f2bf(rres - bf2f(h));
    } else {
        out[(size_t)row * DE + t] = rres;
    }
}

// ---------------- launch ----------------
extern "C" void kernel_launch(void* const* d_in, const int* in_sizes, int n_in,
                              void* d_out, int out_size, void* d_ws, size_t ws_size,
                              hipStream_t stream)
{
    const float* x   = (const float*)d_in[0];
    const float* adj = (const float*)d_in[1];
    const float* W11 = (const float*)d_in[2];
    const float* a11 = (const float*)d_in[3];
    const float* W12 = (const float*)d_in[4];
    const float* a12 = (const float*)d_in[5];
    const float* W21 = (const float*)d_in[6];
    const float* a21 = (const float*)d_in[7];
    const float* W22 = (const float*)d_in[8];
    const float* a22 = (const float*)d_in[9];
    float* out = (float*)d_out;

    char* ws = (char*)d_ws;
    size_t off = 0;
    int*   cols = (int*)(ws + off);            off += (size_t)NV * MAXNNZ * 4;  // 3 MB
    int*   nnz  = (int*)(ws + off);            off += 16 * 1024;
    float* fs   = (float*)(ws + off);          off += 16 * 1024;
    float* fd   = (float*)(ws + off);          off += 16 * 1024;
    float* Wh   = (float*)(ws + off);          off += (size_t)NV * DE * 4;      // 4 MB
    unsigned short* hh  = (unsigned short*)(ws + off); off += (size_t)NV * DE * 2; // 2 MB
    unsigned short* hl  = (unsigned short*)(ws + off); off += (size_t)NV * DE * 2; // 2 MB
    unsigned short* BtH = (unsigned short*)(ws + off); off += (size_t)DE * NV * 2; // 2 MB
    unsigned short* BtL = (unsigned short*)(ws + off); off += (size_t)DE * NV * 2; // 2 MB
    float* Cpart = (float*)(ws + off);         // 32 MB (8 x NV x DE f32)

    build_csr<<<NV / 4, 256, 0, stream>>>(adj, cols, nnz);

    // ---- GAT1 layer 1 (A = x f32, K = 4096, split-K = 8) ----
    transp_split<<<dim3(NV / 32, DE / 32), 256, 0, stream>>>(W11, BtH, BtL, NV);
    gemm_bt<false><<<2 * 8 * 32, 256, 0, stream>>>(x, nullptr, nullptr, BtH, BtL,
                                                   Cpart, NV, NV / 8);
    reduce_fsd<<<NV / 4, 256, 0, stream>>>(Cpart, a11, Wh, fs, fd, 8);
    attn_spmm<0, true><<<NV, 256, 0, stream>>>(Wh, fs, fd, cols, nnz, nullptr, hh, hl);

    // ---- GAT1 layer 2 + fused ReLU (relu(elu(z)) == relu(z)) ----
    transp_split<<<dim3(DE / 32, DE / 32), 256, 0, stream>>>(W12, BtH, BtL, DE);
    gemm_bt<true><<<2 * 4 * 32, 256, 0, stream>>>(nullptr, hh, hl, BtH, BtL,
                                                  Cpart, DE, DE / 4);
    reduce_fsd<<<NV / 4, 256, 0, stream>>>(Cpart, a12, Wh, fs, fd, 4);
    attn_spmm<1, true><<<NV, 256, 0, stream>>>(Wh, fs, fd, cols, nnz, nullptr, hh, hl);

    // ---- GAT2 layer 1 ----
    transp_split<<<dim3(DE / 32, DE / 32), 256, 0, stream>>>(W21, BtH, BtL, DE);
    gemm_bt<true><<<2 * 4 * 32, 256, 0, stream>>>(nullptr, hh, hl, BtH, BtL,
                                                  Cpart, DE, DE / 4);
    reduce_fsd<<<NV / 4, 256, 0, stream>>>(Cpart, a21, Wh, fs, fd, 4);
    attn_spmm<0, true><<<NV, 256, 0, stream>>>(Wh, fs, fd, cols, nnz, nullptr, hh, hl);

    // ---- GAT2 layer 2 -> output ----
    transp_split<<<dim3(DE / 32, DE / 32), 256, 0, stream>>>(W22, BtH, BtL, DE);
    gemm_bt<true><<<2 * 4 * 32, 256, 0, stream>>>(nullptr, hh, hl, BtH, BtL,
                                                  Cpart, DE, DE / 4);
    reduce_fsd<<<NV / 4, 256, 0, stream>>>(Cpart, a22, Wh, fs, fd, 4);
    attn_spmm<0, false><<<NV, 256, 0, stream>>>(Wh, fs, fd, cols, nnz, out, nullptr, nullptr);
}